// Round 10
// baseline (228.090 us; speedup 1.0000x reference)
//
#include <hip/hip_runtime.h>
#include <math.h>

// OrbitalCofactorAntiequivarianceLayer kernels for MI355X (gfx950).
// B=4096, NSPIN=2, NPS=16, D=256, NION=8, DIM=3.
//
// R15 -> R16: five structurally different load schedules (LDS-staged, direct,
// twin-ILP, W-in-LDS, depth-4 reg ring) all pin cof_matrix at ~62us =
// ~one 64B line per ~20 cyc per CU -- a per-CU outstanding-request ceiling
// on the VGPR-return VMEM path. This round bypasses that path entirely:
// x is staged with __builtin_amdgcn_global_load_lds (DMA direct-to-LDS,
// width 16), the one mechanism never tried here and the biggest single
// lever in the learn_hip GEMM ladder. Four 4KB d-quarters per pair,
// double-buffered, counted vmcnt(4) waits (never drain mid-loop).
// LDS dest linear (wave-uniform base + lane*16); bank swizzle applied on
// the GLOBAL source address (chunk ^= R&7 -> 2-way = free on ds_read).
// FMA operands/order unchanged -> bit-identical. cof_lu unchanged.

#define GLOAD_LDS16(gp, lp)                                                   \
  __builtin_amdgcn_global_load_lds(                                           \
      (const __attribute__((address_space(1))) void*)(gp),                    \
      (__attribute__((address_space(3))) void*)(lp), 16, 0, 0)

// ---------------- kernel 1: M = (x@W + b) * env -> ws ----------------
__global__ __launch_bounds__(256)
void cof_matrix(const float* __restrict__ eq,    // (B,32,256)
                const float* __restrict__ rei,   // (B,32,8,3)
                const float* __restrict__ Wm,    // (2,256,16)
                const float* __restrict__ bb,    // (2,16)
                const float* __restrict__ edim,  // (2,8,16,3,3)
                const float* __restrict__ eion,  // (2,8,16)
                float* __restrict__ ws)          // (8192, 256) = M per pair
{
  __shared__ __align__(16) float Wp[256 * 20];    // W[sp], row stride 20 (20 KB)
  __shared__ __align__(16) float Gl[8 * 6 * 16];  // Gram coeffs, SoA [i][c6][o]
  __shared__ __align__(16) float Xs[4][2][1024];  // per-wave x quarter dbuf (32 KB)
  __shared__ __align__(16) float Ml[4 * 320];     // per-wave M (16 rows x stride 20)

  const int tid   = threadIdx.x;
  const int lane  = tid & 63;
  const int wv    = tid >> 6;
  const int blk   = blockIdx.x;
  const int sp    = blk >> 10;           // spin index
  const int bbase = (blk & 1023) * 4;

  const float* wb = Wm + (size_t)sp * 4096;

  // ---- W -> LDS (coalesced read, stride-20 write), once per block ----
  #pragma unroll
  for (int t = 0; t < 4; ++t) {
    const int idx = t * 256 + tid;       // float4 index over [256][16]
    const int d   = idx >> 2;
    const int c4  = idx & 3;
    float4 v = ((const float4*)wb)[idx];
    *(float4*)(Wp + d * 20 + c4 * 4) = v;
  }

  // ---- Gram precompute: G = A^T A per (i,o), cross terms pre-doubled ----
  if (tid < 128) {
    const int i = tid >> 4, o = tid & 15;
    const float* A = edim + (((size_t)sp * 8 + i) * 16 + o) * 9;
    const float a0=A[0],a1=A[1],a2=A[2],a3=A[3],a4=A[4],a5=A[5],a6=A[6],a7=A[7],a8=A[8];
    float* Gp = Gl + i * 96 + o;
    Gp[0]  = a0*a0 + a3*a3 + a6*a6;
    Gp[16] = a1*a1 + a4*a4 + a7*a7;
    Gp[32] = a2*a2 + a5*a5 + a8*a8;
    Gp[48] = 2.f*(a0*a1 + a3*a4 + a6*a7);
    Gp[64] = 2.f*(a0*a2 + a3*a5 + a6*a8);
    Gp[80] = 2.f*(a1*a2 + a4*a5 + a7*a8);
  }
  __syncthreads();   // also drains vmcnt -> clean baseline for counted waits

  const int bidx = bbase + wv;
  const int cch  = lane >> 4;        // K-chunk within a 16-float group
  const int nb   = (lane >> 2) & 3;  // row-tile
  const int ob   = lane & 3;         // col-tile
  const int rl   = lane >> 4;        // staging: row-local within group of 4
  const int sl   = lane & 15;        // staging: chunk slot within 64-float span

  const float* xb = eq + ((size_t)bidx * 32 + sp * 16) * 256;

  float* xwA = &Xs[wv][0][0];
  float* xwB = &Xs[wv][1][0];

  float acc[4][4] = {{0.f,0.f,0.f,0.f},{0.f,0.f,0.f,0.f},
                     {0.f,0.f,0.f,0.f},{0.f,0.f,0.f,0.f}};

  // ---- Phase A: y = xs @ W. x staged via global_load_lds DMA in 4KB
  // d-quarters (quarter qt = cols qt*64..qt*64+63 of all 16 rows).
  // LDS layout: row R at R*64 floats; slot s of row R holds global chunk
  // s ^ (R&7) (source-side swizzle; involution). Reads: 2-way conflicts.
  // Stage instr i covers rows 4i..4i+3: dest uniform = buf + i*256 floats
  // (HW adds lane*16B); src per lane = row (4i+rl), chunk sl^(R&7).
#define STAGEQ(bufp, qt)                                                      \
  { _Pragma("unroll")                                                         \
    for (int i = 0; i < 4; ++i) {                                             \
      const int R_ = 4 * i + rl;                                              \
      const float* src_ = xb + (size_t)R_ * 256 + (qt) * 64                   \
                          + ((sl ^ (R_ & 7)) * 4);                            \
      GLOAD_LDS16(src_, (bufp) + i * 256);                                    \
    } }

#define COMPQ(bufp, qt)                                                       \
  _Pragma("unroll")                                                           \
  for (int qq = 0; qq < 4; ++qq) {                                            \
    const int q  = (qt) * 4 + qq;                                             \
    const int dg = q * 16 + cch * 4;                                          \
    float wr4[4][4];                                                          \
    _Pragma("unroll")                                                         \
    for (int j = 0; j < 4; ++j) {                                             \
      float4 t = *(const float4*)(Wp + (dg + j) * 20 + 4 * ob);               \
      wr4[j][0]=t.x; wr4[j][1]=t.y; wr4[j][2]=t.z; wr4[j][3]=t.w;             \
    }                                                                         \
    float xr[4][4];                                                           \
    _Pragma("unroll")                                                         \
    for (int r = 0; r < 4; ++r) {                                             \
      const int R_ = 4 * nb + r;                                              \
      const int ck = (qq * 4 + cch) ^ (R_ & 7);                               \
      float4 t = *(const float4*)((bufp) + R_ * 64 + ck * 4);                 \
      xr[r][0]=t.x; xr[r][1]=t.y; xr[r][2]=t.z; xr[r][3]=t.w;                 \
    }                                                                         \
    _Pragma("unroll")                                                         \
    for (int r = 0; r < 4; ++r)                                               \
      _Pragma("unroll")                                                       \
      for (int j = 0; j < 4; ++j)                                             \
        _Pragma("unroll")                                                     \
        for (int c2 = 0; c2 < 4; ++c2)                                        \
          acc[r][c2] = fmaf(xr[r][j], wr4[j][c2], acc[r][c2]);                \
  }

  STAGEQ(xwA, 0)
  STAGEQ(xwB, 1)
  asm volatile("s_waitcnt vmcnt(4)" ::: "memory");  // quarter 0 landed
  __builtin_amdgcn_sched_barrier(0);
  COMPQ(xwA, 0)
  STAGEQ(xwA, 2)
  asm volatile("s_waitcnt vmcnt(4)" ::: "memory");  // quarter 1 landed
  __builtin_amdgcn_sched_barrier(0);
  COMPQ(xwB, 1)
  STAGEQ(xwB, 3)
  asm volatile("s_waitcnt vmcnt(4)" ::: "memory");  // quarter 2 landed
  __builtin_amdgcn_sched_barrier(0);
  COMPQ(xwA, 2)
  asm volatile("s_waitcnt vmcnt(0)" ::: "memory");  // quarter 3 landed
  __builtin_amdgcn_sched_barrier(0);
  COMPQ(xwB, 3)

#undef STAGEQ
#undef COMPQ

  // reduce over K-chunks (lane bits 4-5)
  #pragma unroll
  for (int r = 0; r < 4; ++r)
    #pragma unroll
    for (int c2 = 0; c2 < 4; ++c2) {
      float v = acc[r][c2];
      v += __shfl_xor(v, 16);
      v += __shfl_xor(v, 32);
      acc[r][c2] = v;
    }

  // y (pre-env) in this wave's LDS slice, 16 rows, stride 20 floats.
  float* Mw = Ml + wv * 320;
  {
    float4 bv = *(const float4*)(bb + sp * 16 + 4 * ob);
    if (lane < 16) {
      #pragma unroll
      for (int r = 0; r < 4; ++r) {
        float4 v = make_float4(acc[r][0] + bv.x, acc[r][1] + bv.y,
                               acc[r][2] + bv.z, acc[r][3] + bv.w);
        *(float4*)(Mw + (4 * nb + r) * 20 + 4 * ob) = v;
      }
    }
  }

  // ---- Phase C: envelope; M = y * env -> ws (coalesced float4 store) ----
  {
    const int n = lane >> 2;           // row 0..15, cols 4*ob..4*ob+3
    const float* rp = rei + ((size_t)bidx * 32 + sp * 16 + n) * 24;
    float rv[24];
    #pragma unroll
    for (int t4 = 0; t4 < 6; ++t4) {
      float4 t = *(const float4*)(rp + t4 * 4);
      rv[t4*4+0]=t.x; rv[t4*4+1]=t.y; rv[t4*4+2]=t.z; rv[t4*4+3]=t.w;
    }
    float4 env = make_float4(0.f, 0.f, 0.f, 0.f);
    #pragma unroll
    for (int i = 0; i < 8; ++i) {
      const float r0 = rv[i*3], r1 = rv[i*3+1], r2 = rv[i*3+2];
      const float rr0 = r0*r0, rr1 = r1*r1, rr2 = r2*r2;
      const float rr3 = r0*r1, rr4 = r0*r2, rr5 = r1*r2;
      const float* Gp = Gl + i * 96 + 4 * ob;
      const float4 q00 = *(const float4*)(Gp);
      const float4 q11 = *(const float4*)(Gp + 16);
      const float4 q22 = *(const float4*)(Gp + 32);
      const float4 q01 = *(const float4*)(Gp + 48);
      const float4 q02 = *(const float4*)(Gp + 64);
      const float4 q12 = *(const float4*)(Gp + 80);
      const float4 io  = *(const float4*)(eion + ((size_t)sp * 8 + i) * 16 + 4 * ob);
#define ENVC(c) { float n2 = q00.c*rr0 + q11.c*rr1 + q22.c*rr2 \
                           + q01.c*rr3 + q02.c*rr4 + q12.c*rr5; \
                  n2 = fmaxf(n2, 0.f); \
                  env.c += __expf(-sqrtf(n2)) * io.c; }
      ENVC(x) ENVC(y) ENVC(z) ENVC(w)
#undef ENVC
    }
    const float* mp = Mw + n * 20 + 4 * ob;
    float4 y = *(const float4*)mp;
    const size_t pair = (size_t)bidx * 2 + sp;
    // lanes 0..63 -> offsets 0,4,...,252: fully coalesced 1KB/wave store
    *(float4*)(ws + pair * 256 + n * 16 + 4 * ob) =
        make_float4(y.x * env.x, y.y * env.y, y.z * env.z, y.w * env.w);
  }
}

// ---------------- kernel 2: cofactor via 16-lane LU ----------------
// One wave per block (64 threads); four 16-lane groups handle FOUR distinct
// pairs. A = M^T, fp32 LU with virtual partial pivoting;
// cof[i] = M[i,0]*det*x[i], x = A^{-1} e0 (= row 0 of M^{-1}).
__global__ __launch_bounds__(64)
void cof_lu(const float* __restrict__ ws,   // (8192, 256)
            float* __restrict__ out)        // (B,2,16) = (8192,16)
{
  const int lane = threadIdx.x;
  const int g  = lane >> 4;        // group -> pair within block
  const int r  = lane & 15;        // my row of A (= column r of M)
  const int gb = lane & 48;        // group base for shuffles
  const size_t pair = (size_t)blockIdx.x * 4 + g;
  const float* mg = ws + pair * 256;

  float a[16];
  #pragma unroll
  for (int c = 0; c < 16; ++c) a[c] = mg[c * 16 + r];

  float det = 1.0f;
  int sign = 0;
  unsigned retired = 0;
  unsigned pp0 = 0, pp1 = 0;       // packed pivot indices, 4 bits each
  int srr = 0;
  float accf = (r == 0) ? 1.0f : 0.0f;  // forward rhs (P e0 component)
  float acc2 = 0.0f;                    // z captured at my retirement

  #pragma unroll
  for (int k = 0; k < 16; ++k) {
    const bool act = ((retired >> r) & 1u) == 0u;
    const float av = act ? fabsf(a[k]) : 0.0f;
    unsigned pk = (__float_as_uint(av) & 0xFFFFFFF0u) | (unsigned)r;
    #pragma unroll
    for (int m = 1; m <= 8; m <<= 1) {
      unsigned o2 = __shfl_xor(pk, m);
      pk = (pk > o2) ? pk : o2;
    }
    const int p = (int)(pk & 15u);
    if (k < 8) pp0 |= (unsigned)p << (4 * k);
    else       pp1 |= (unsigned)p << (4 * (k - 8));
    float pv = __shfl(a[k], gb | p);
    if (fabsf(pv) < 1e-30f) pv = (pv < 0.0f) ? -1e-30f : 1e-30f;
    det *= pv;
    retired |= (1u << p);
    sign ^= (int)(__popc((~retired) & ((1u << p) - 1u)) & 1u);
    if (r == p) srr = k;
    const bool upd = act && (r != p);
    float m2 = 0.0f;
    if (upd) { m2 = a[k] / pv; a[k] = m2; }
    #pragma unroll
    for (int c = k + 1; c < 16; ++c) {
      float bcv = __shfl(a[c], gb | p);
      if (upd) a[c] = fmaf(-m2, bcv, a[c]);
    }
    // fused forward solve L z = P e0
    float zk = __shfl(accf, gb | p);
    if (r == p) acc2 = zk;
    if (upd) accf = fmaf(-m2, zk, accf);
  }
  if (sign) det = -det;

  // backward solve U x = z
  float myx = 0.0f;
  #pragma unroll
  for (int j = 15; j >= 0; --j) {
    float t = acc2 / a[j];                   // valid on pivot lane of step j
    const int pj = (int)(((j >= 8) ? (pp1 >> (4 * (j - 8)))
                                   : (pp0 >> (4 * j))) & 15u);
    float xj = __shfl(t, gb | pj);
    if (srr < j) acc2 = fmaf(-a[j], xj, acc2);
    if (r == j) myx = xj;
  }

  const float mi0 = mg[r * 16];              // M[r][0]
  out[pair * 16 + r] = mi0 * det * myx;      // all 64 lanes: 4 pairs x 16
}

extern "C" void kernel_launch(void* const* d_in, const int* in_sizes, int n_in,
                              void* d_out, int out_size, void* d_ws, size_t ws_size,
                              hipStream_t stream) {
  (void)in_sizes; (void)n_in; (void)out_size; (void)ws_size;
  const float* eq   = (const float*)d_in[0];
  const float* rei  = (const float*)d_in[1];
  const float* Wm   = (const float*)d_in[2];
  const float* bb   = (const float*)d_in[3];
  const float* edim = (const float*)d_in[4];
  const float* eion = (const float*)d_in[5];
  float* out = (float*)d_out;
  float* ws  = (float*)d_ws;   // needs 8192*256*4 = 8 MB
  hipLaunchKernelGGL(cof_matrix, dim3(2048), dim3(256), 0, stream,
                     eq, rei, Wm, bb, edim, eion, ws);
  hipLaunchKernelGGL(cof_lu, dim3(2048), dim3(64), 0, stream, ws, out);
}